// Round 7
// baseline (1813.086 us; speedup 1.0000x reference)
//
#include <hip/hip_runtime.h>
#include <hip/hip_bf16.h>
#include <stdint.h>

// N=8192, C1=512, C2=128, M=4, B=256, TOPK=40, R=B*M*M=4096
#define EPSF 1e-5f
#define RSQ 0.08838834764831845f  // 1/sqrt(128)

typedef __bf16 b16x8 __attribute__((ext_vector_type(8)));
typedef float f32x4 __attribute__((ext_vector_type(4)));
typedef unsigned short u16x8 __attribute__((ext_vector_type(8)));

static __device__ __forceinline__ unsigned short f2bf(float f) {
  __hip_bfloat16 h = __float2bfloat16(f);
  return __builtin_bit_cast(unsigned short, h);
}
static __device__ __forceinline__ float bf2f(unsigned short u) {
  union { unsigned int i; float f; } x; x.i = ((unsigned int)u) << 16; return x.f;
}

// ---------------- RNG (JAX threefry, partitionable) ----------------
__device__ __forceinline__ void threefry2x32(uint32_t k0, uint32_t k1,
                                             uint32_t c0, uint32_t c1,
                                             uint32_t& o0, uint32_t& o1) {
  const uint32_t ks2 = k0 ^ k1 ^ 0x1BD11BDAu;
  uint32_t x0 = c0 + k0, x1 = c1 + k1;
#define TFR(r) { x0 += x1; x1 = (x1 << (r)) | (x1 >> (32 - (r))); x1 ^= x0; }
  TFR(13) TFR(15) TFR(26) TFR(6)
  x0 += k1;  x1 += ks2 + 1u;
  TFR(17) TFR(29) TFR(16) TFR(24)
  x0 += ks2; x1 += k0 + 2u;
  TFR(13) TFR(15) TFR(26) TFR(6)
  x0 += k0;  x1 += k1 + 3u;
  TFR(17) TFR(29) TFR(16) TFR(24)
  x0 += k1;  x1 += ks2 + 4u;
  TFR(13) TFR(15) TFR(26) TFR(6)
  x0 += ks2; x1 += k0 + 5u;
#undef TFR
  o0 = x0; o1 = x1;
}

// rank-based permutation: invperm[s][v] = rank2[rank1[v]]
__global__ __launch_bounds__(256) void rank_kernel(int* __restrict__ rankbuf) {
  __shared__ uint32_t bits[8192];
  const int chunk = blockIdx.x;
  const int round = blockIdx.y;
  const int s     = blockIdx.z;
  const int t = threadIdx.x, l = t & 63, w = t >> 6;
  uint32_t ka, kb;
  {
    uint32_t k1a, k1b;
    threefry2x32(0u, (uint32_t)s, 0u, 0u, k1a, k1b);
    if (round == 0) threefry2x32(0u, (uint32_t)s, 0u, 1u, ka, kb);
    else            threefry2x32(k1a, k1b, 0u, 1u, ka, kb);
  }
  for (int j = t; j < 8192; j += 256) {
    uint32_t t0, t1;
    threefry2x32(ka, kb, 0u, (uint32_t)j, t0, t1);
    bits[j] = t1;
  }
  __syncthreads();
  const int base = chunk * 256 + w * 64;
  const int i = base + l;
  const uint32_t myb = bits[i];
  const uint4* b4 = (const uint4*)bits;
  int rk = 0;
  const int lo = base >> 2;
#pragma unroll 4
  for (int j4 = 0; j4 < lo; j4++) {
    const uint4 b = b4[j4];
    rk += (b.x <= myb) + (b.y <= myb) + (b.z <= myb) + (b.w <= myb);
  }
#pragma unroll
  for (int j4 = lo; j4 < lo + 16; j4++) {
    const uint4 b = b4[j4];
    const int j = j4 * 4;
    rk += (b.x < myb) + ((b.x == myb) && (j     < i));
    rk += (b.y < myb) + ((b.y == myb) && (j + 1 < i));
    rk += (b.z < myb) + ((b.z == myb) && (j + 2 < i));
    rk += (b.w < myb) + ((b.w == myb) && (j + 3 < i));
  }
#pragma unroll 4
  for (int j4 = lo + 16; j4 < 2048; j4++) {
    const uint4 b = b4[j4];
    rk += (b.x < myb) + (b.y < myb) + (b.z < myb) + (b.w < myb);
  }
  rankbuf[(s * 2 + round) * 8192 + i] = rk;
}

__global__ __launch_bounds__(256) void compose_kernel(const int* __restrict__ rankbuf,
                                                      int* __restrict__ invperm) {
  const int s = blockIdx.y;
  const int v = blockIdx.x * 256 + threadIdx.x;
  const int* r1 = rankbuf + s * 16384;
  const int* r2 = r1 + 8192;
  invperm[s * 8192 + v] = r2[r1[v]];
}

// ---------------- q path ----------------
__global__ __launch_bounds__(256) void qraw_kernel(const float* __restrict__ x,
    const float* __restrict__ Wq, const float* __restrict__ bq,
    float* __restrict__ qraw) {
  __shared__ float ea[16][128];
  __shared__ float wq[128][132];
  const int t = threadIdx.x;
  const int g = blockIdx.x;
  const int m2 = blockIdx.y;
  for (int i = t; i < 512; i += 256) {
    float4 xx = *(const float4*)(x + (size_t)g * 2048 + i * 4);
    *(float4*)&ea[i >> 5][(i & 31) * 4] = xx;
  }
  for (int i = t; i < 4096; i += 256) {
    float4 ww = *(const float4*)(Wq + (size_t)m2 * 16384 + i * 4);
    *(float4*)&wq[i >> 5][(i & 31) * 4] = ww;
  }
  __syncthreads();
  const int row = t >> 4, j = t & 15;
  float acc[8] = {0.f,0.f,0.f,0.f,0.f,0.f,0.f,0.f};
  for (int d = 0; d < 128; d++) {
    const float xv = ea[row][d];
#pragma unroll
    for (int cc = 0; cc < 8; cc++) acc[cc] += xv * wq[j + cc * 16][d];
  }
  const int r = (g * 16 + row) * 4 + m2;
#pragma unroll
  for (int cc = 0; cc < 8; cc++) {
    const int c = j + cc * 16;
    qraw[(size_t)r * 128 + c] = acc[cc] + bq[m2 * 128 + c];
  }
}

__global__ __launch_bounds__(256) void bnpart_kernel(const float* __restrict__ qraw,
                                                     float* __restrict__ bnpart) {
  __shared__ float a1[256], a2[256];
  const int t = threadIdx.x, c = t & 127, h = t >> 7;
  float s1 = 0.f, s2 = 0.f;
  for (int i = 0; i < 64; i++) {
    float xv = qraw[(size_t)(blockIdx.x * 128 + h + 2 * i) * 128 + c];
    s1 += xv; s2 += xv * xv;
  }
  a1[t] = s1; a2[t] = s2;
  __syncthreads();
  if (t < 128) {
    bnpart[blockIdx.x * 256 + t]       = a1[t] + a1[t + 128];
    bnpart[blockIdx.x * 256 + 128 + t] = a2[t] + a2[t + 128];
  }
}

__global__ void bnfin_kernel(const float* __restrict__ bnpart,
                             const float* __restrict__ gamma,
                             const float* __restrict__ beta,
                             float* __restrict__ bnstat) {
  const int c = threadIdx.x;
  float s1 = 0.f, s2 = 0.f;
  for (int i = 0; i < 32; i++) { s1 += bnpart[i * 256 + c]; s2 += bnpart[i * 256 + 128 + c]; }
  const float mu  = s1 * (1.0f / 4096.0f);
  const float var = s2 * (1.0f / 4096.0f) - mu * mu;
  const float sc  = rsqrtf(var + EPSF) * gamma[c];
  bnstat[c]       = sc;
  bnstat[128 + c] = beta[c] - mu * sc;
}

__global__ __launch_bounds__(256) void qnorm_kernel(const float* __restrict__ qraw,
    const float* __restrict__ bnstat, float* __restrict__ outq,
    unsigned short* __restrict__ qb) {
  const int idx4 = blockIdx.x * 256 + threadIdx.x;
  float4 xv = *(const float4*)(qraw + (size_t)idx4 * 4);
  const int c0 = (idx4 * 4) & 127;
  float4 sc = *(const float4*)(bnstat + c0);
  float4 sh = *(const float4*)(bnstat + 128 + c0);
  float4 o;
  o.x = xv.x * sc.x + sh.x; o.y = xv.y * sc.y + sh.y;
  o.z = xv.z * sc.z + sh.z; o.w = xv.w * sc.w + sh.w;
  *(float4*)(outq + (size_t)idx4 * 4) = o;
  ushort4 ob;
  ob.x = f2bf(o.x); ob.y = f2bf(o.y); ob.z = f2bf(o.z); ob.w = f2bf(o.w);
  *(ushort4*)(qb + (size_t)idx4 * 4) = ob;
}

// ---------------- LN(emb) -> kbuf, emb@Wv^T+bv -> vbuf ----------------
__global__ __launch_bounds__(256) void lnv_kernel(const float* __restrict__ emb,
    const float* __restrict__ Wv, const float* __restrict__ bv,
    const float* __restrict__ lng, const float* __restrict__ lnb,
    float* __restrict__ kbuf, float* __restrict__ vbuf) {
  __shared__ float ea[16][128];
  __shared__ float wv[128][132];
  const int t = threadIdx.x;
  const int r0 = blockIdx.x * 16;
  for (int i = t; i < 512; i += 256) {
    float4 xx = *(const float4*)(emb + (size_t)r0 * 128 + i * 4);
    *(float4*)&ea[i >> 5][(i & 31) * 4] = xx;
  }
  for (int i = t; i < 4096; i += 256) {
    float4 ww = *(const float4*)(Wv + (size_t)i * 4);
    *(float4*)&wv[i >> 5][(i & 31) * 4] = ww;
  }
  __syncthreads();
  const int row = t >> 4, j = t & 15;
  float s1 = 0.f, s2 = 0.f;
#pragma unroll
  for (int m = 0; m < 8; m++) { float xv = ea[row][j + m * 16]; s1 += xv; s2 += xv * xv; }
#pragma unroll
  for (int off = 8; off; off >>= 1) {
    s1 += __shfl_xor(s1, off, 16);
    s2 += __shfl_xor(s2, off, 16);
  }
  const float mu   = s1 * 0.0078125f;
  const float var  = s2 * 0.0078125f - mu * mu;
  const float rstd = rsqrtf(var + EPSF);
#pragma unroll
  for (int m = 0; m < 8; m++) {
    const int d = j + m * 16;
    kbuf[(size_t)(r0 + row) * 128 + d] = (ea[row][d] - mu) * rstd * lng[d] + lnb[d];
  }
  float acc[8] = {0.f,0.f,0.f,0.f,0.f,0.f,0.f,0.f};
  for (int d = 0; d < 128; d++) {
    const float xv = ea[row][d];
#pragma unroll
    for (int cc = 0; cc < 8; cc++) acc[cc] += xv * wv[j + cc * 16][d];
  }
#pragma unroll
  for (int cc = 0; cc < 8; cc++) {
    const int c = j + cc * 16;
    vbuf[(size_t)(r0 + row) * 128 + c] = acc[cc] + bv[c];
  }
}

// ---------------- bf16 transposes (merged): y=0 -> kT, y=1 -> vT ----------------
__global__ __launch_bounds__(256) void kvtrans_kernel(const float* __restrict__ kbuf,
    const float* __restrict__ vbuf, unsigned short* __restrict__ kT,
    unsigned short* __restrict__ vT) {
  __shared__ __attribute__((aligned(16))) unsigned short sbuf[9216];
  const int b = blockIdx.x, t = threadIdx.x;
  if (blockIdx.y == 0) {
    unsigned short (*s)[136] = (unsigned short (*)[136])sbuf;
    const int k = t >> 1, half = t & 1;
    const float* src = kbuf + (size_t)(k * 64 + (b >> 1)) * 128 + (b & 1) * 64 + half * 32;
#pragma unroll
    for (int i = 0; i < 8; i++) {
      float4 v = *(const float4*)(src + i * 4);
      const int dn = half * 32 + i * 4;
      s[dn + 0][k] = f2bf(v.x); s[dn + 1][k] = f2bf(v.y);
      s[dn + 2][k] = f2bf(v.z); s[dn + 3][k] = f2bf(v.w);
    }
    __syncthreads();
    const int dn = t >> 2, q = t & 3;
    unsigned short* dst = kT + (size_t)(b * 64 + dn) * 128 + q * 32;
#pragma unroll
    for (int j = 0; j < 4; j++)
      *(int4*)(dst + j * 8) = *(const int4*)&s[dn][q * 32 + j * 8];
  } else {
    unsigned short (*s)[72] = (unsigned short (*)[72])sbuf;
    const int i0 = b * 64;
    const int di = t >> 2, q = t & 3;
    const float* src = vbuf + (size_t)(i0 + di) * 128 + q * 32;
#pragma unroll
    for (int i = 0; i < 8; i++) {
      float4 v = *(const float4*)(src + i * 4);
      const int c = q * 32 + i * 4;
      s[c + 0][di] = f2bf(v.x); s[c + 1][di] = f2bf(v.y);
      s[c + 2][di] = f2bf(v.z); s[c + 3][di] = f2bf(v.w);
    }
    __syncthreads();
    const int c = t >> 1, half = t & 1;
    unsigned short* dst = vT + (size_t)c * 8192 + i0 + half * 32;
#pragma unroll
    for (int j = 0; j < 4; j++)
      *(int4*)(dst + j * 8) = *(const int4*)&s[c][half * 32 + j * 8];
  }
}

// ---------------- attn_flash: online-softmax QK^T + PV + candidates ----------------
// grid (8, 64), block 256 (4 waves, 2 row x 2 col). Per block: 64 rows x 1024 cols.
// Running max m is SHARED per row across the two wc waves each tile (the shared
// P tile demands one consistent normalization).
__global__ __launch_bounds__(256, 2) void attn_flash(
    const unsigned short* __restrict__ qb, const unsigned short* __restrict__ kT,
    const unsigned short* __restrict__ vT, float* __restrict__ pvpart,
    float* __restrict__ maxpart, float* __restrict__ expsumpart,
    unsigned long long* __restrict__ candbuf, int* __restrict__ cnt) {
  __shared__ __attribute__((aligned(16))) unsigned short kvt[16384];  // [128][128] 32KB
  __shared__ __attribute__((aligned(16))) unsigned short pt[8192];    // [64][128] 16KB
  __shared__ float mred[64][2], esred[64][2];
  const int t = threadIdx.x, l = t & 63, w = t >> 6;
  const int bx = blockIdx.x;          // k-chunk, 1024 cols
  const int r0g = blockIdx.y * 64;    // global row base
  const int n0 = bx * 1024;
  const int wr = w >> 1, wc = w & 1;
  float m[2][4], es[2][4];
  f32x4 pv[2][4];
#pragma unroll
  for (int i = 0; i < 2; i++)
#pragma unroll
    for (int jj = 0; jj < 4; jj++) { m[i][jj] = -3.0e38f; es[i][jj] = 0.f; }
#pragma unroll
  for (int i = 0; i < 2; i++)
#pragma unroll
    for (int j = 0; j < 4; j++) pv[i][j] = (f32x4){0.f, 0.f, 0.f, 0.f};

  for (int ct = 0; ct < 8; ct++) {
    __syncthreads();
    // stage K tile [128 n][128 k], pre-swizzled source
#pragma unroll
    for (int it = 0; it < 8; it++) {
      const int c = it * 256 + t;
      const int row = c >> 4, ch = c & 15, chs = ch ^ (row & 7);
      const unsigned short* g = kT + (size_t)(n0 + ct * 128 + row) * 128 + chs * 8;
      __builtin_amdgcn_global_load_lds((const __attribute__((address_space(1))) void*)g,
          (__attribute__((address_space(3))) void*)(kvt + (size_t)(it * 256 + w * 64) * 8), 16, 0, 0);
    }
    __syncthreads();
    // QK^T for this ct tile
    f32x4 sacc[2][4];
#pragma unroll
    for (int i = 0; i < 2; i++)
#pragma unroll
      for (int j = 0; j < 4; j++) sacc[i][j] = (f32x4){0.f, 0.f, 0.f, 0.f};
#pragma unroll
    for (int ks = 0; ks < 4; ks++) {
      b16x8 a0 = __builtin_bit_cast(b16x8,
          *(const u16x8*)(qb + (size_t)(r0g + wr * 32 + (l & 15)) * 128 + ks * 32 + (l >> 4) * 8));
      b16x8 a1 = __builtin_bit_cast(b16x8,
          *(const u16x8*)(qb + (size_t)(r0g + wr * 32 + 16 + (l & 15)) * 128 + ks * 32 + (l >> 4) * 8));
#pragma unroll
      for (int j = 0; j < 4; j++) {
        const int cl = wc * 64 + j * 16 + (l & 15);
        const int ch = (ks * 4 + (l >> 4)) ^ (cl & 7);
        b16x8 bf = __builtin_bit_cast(b16x8, *(const u16x8*)&kvt[cl * 128 + ch * 8]);
        sacc[0][j] = __builtin_amdgcn_mfma_f32_16x16x32_bf16(a0, bf, sacc[0][j], 0, 0, 0);
        sacc[1][j] = __builtin_amdgcn_mfma_f32_16x16x32_bf16(a1, bf, sacc[1][j], 0, 0, 0);
      }
    }
    // per-row tile max (this wave's 64 cols), then share across wc halves
    float tmv[2][4];
#pragma unroll
    for (int i = 0; i < 2; i++)
#pragma unroll
      for (int jj = 0; jj < 4; jj++) {
        float tm = fmaxf(fmaxf(sacc[i][0][jj], sacc[i][1][jj]),
                         fmaxf(sacc[i][2][jj], sacc[i][3][jj])) * RSQ;
#pragma unroll
        for (int off = 8; off; off >>= 1) tm = fmaxf(tm, __shfl_xor(tm, off));
        tmv[i][jj] = tm;
        if ((l & 15) == 0) mred[wr * 32 + i * 16 + (l >> 4) * 4 + jj][wc] = tm;
      }
    __syncthreads();
    // online softmax (shared nm) + P tile + candidates
#pragma unroll
    for (int i = 0; i < 2; i++) {
#pragma unroll
      for (int jj = 0; jj < 4; jj++) {
        const int prow = wr * 32 + i * 16 + (l >> 4) * 4 + jj;
        const float other = mred[prow][wc ^ 1];
        const float nm = fmaxf(m[i][jj], fmaxf(tmv[i][jj], other));
        const float f = expf(m[i][jj] - nm);
        es[i][jj] *= f;
#pragma unroll
        for (int j = 0; j < 4; j++) pv[i][j][jj] *= f;
#pragma unroll
        for (int j = 0; j < 4; j++) {
          const float logit = sacc[i][j][jj] * RSQ;
          const float p = expf(logit - nm);
          es[i][jj] += p;
          const int colb = wc * 64 + j * 16 + (l & 15);
          const int physc = (((colb >> 3) ^ (prow & 7)) << 3) | (colb & 7);
          pt[prow * 128 + physc] = f2bf(p);
          if (logit >= nm - 2.0f) {
            const int rg = r0g + prow;
            const int pos = atomicAdd(&cnt[rg * 8 + bx], 1);
            if (pos < 160) {
              const uint32_t sb = __float_as_uint(logit);
              const uint32_t mk = (sb & 0x80000000u) ? ~sb : (sb | 0x80000000u);
              candbuf[((size_t)rg * 8 + bx) * 160 + pos] =
                  ((unsigned long long)(~mk) << 32) | (unsigned)(n0 + ct * 128 + colb);
            }
          }
        }
        m[i][jj] = nm;
      }
    }
    __syncthreads();
    // stage V tile [128 d][128 k]
#pragma unroll
    for (int it = 0; it < 8; it++) {
      const int c = it * 256 + t;
      const int row = c >> 4, ch = c & 15, chs = ch ^ (row & 7);
      const unsigned short* g = vT + (size_t)row * 8192 + n0 + ct * 128 + chs * 8;
      __builtin_amdgcn_global_load_lds((const __attribute__((address_space(1))) void*)g,
          (__attribute__((address_space(3))) void*)(kvt + (size_t)(it * 256 + w * 64) * 8), 16, 0, 0);
    }
    __syncthreads();
    // PV
#pragma unroll
    for (int ks = 0; ks < 4; ks++) {
      b16x8 paf[2];
#pragma unroll
      for (int i = 0; i < 2; i++) {
        const int rl = wr * 32 + i * 16 + (l & 15);
        const int ch = (ks * 4 + (l >> 4)) ^ (rl & 7);
        paf[i] = __builtin_bit_cast(b16x8, *(const u16x8*)&pt[rl * 128 + ch * 8]);
      }
#pragma unroll
      for (int j = 0; j < 4; j++) {
        const int cl = wc * 64 + j * 16 + (l & 15);
        const int ch = (ks * 4 + (l >> 4)) ^ (cl & 7);
        b16x8 vbf = __builtin_bit_cast(b16x8, *(const u16x8*)&kvt[cl * 128 + ch * 8]);
        pv[0][j] = __builtin_amdgcn_mfma_f32_16x16x32_bf16(paf[0], vbf, pv[0][j], 0, 0, 0);
        pv[1][j] = __builtin_amdgcn_mfma_f32_16x16x32_bf16(paf[1], vbf, pv[1][j], 0, 0, 0);
      }
    }
  }
  // epilogue: combine wc halves (same m on both), store partials, write pv
  __syncthreads();
#pragma unroll
  for (int i = 0; i < 2; i++)
#pragma unroll
    for (int jj = 0; jj < 4; jj++) {
      float e = es[i][jj];
#pragma unroll
      for (int off = 8; off; off >>= 1) e += __shfl_xor(e, off);
      if ((l & 15) == 0) {
        const int row = wr * 32 + i * 16 + (l >> 4) * 4 + jj;
        mred[row][wc] = m[i][jj];
        esred[row][wc] = e;
      }
    }
  __syncthreads();
  if (t < 64) {
    const float m0 = mred[t][0], m1 = mred[t][1];
    const float M = fmaxf(m0, m1);
    const float E = esred[t][0] * expf(m0 - M) + esred[t][1] * expf(m1 - M);
    maxpart[bx * 4096 + r0g + t] = M;
    expsumpart[bx * 4096 + r0g + t] = E;
    mred[t][0] = M;
  }
  __syncthreads();
  float* fb = (float*)kvt;  // 64 x 128 f32 = 32 KB
#pragma unroll
  for (int i = 0; i < 2; i++)
#pragma unroll
    for (int jj = 0; jj < 4; jj++) {
      const int row = wr * 32 + i * 16 + (l >> 4) * 4 + jj;
      const float sc = expf(m[i][jj] - mred[row][0]);
#pragma unroll
      for (int j = 0; j < 4; j++)
        fb[row * 128 + wc * 64 + j * 16 + (l & 15)] = pv[i][j][jj] * sc;
    }
  __syncthreads();
#pragma unroll
  for (int kk = 0; kk < 8; kk++) {
    const int idx4 = kk * 256 + t;
    const int row = idx4 >> 5, c4 = idx4 & 31;
    *(float4*)(pvpart + ((size_t)bx * 4096 + r0g + row) * 128 + c4 * 4) = *(const float4*)&fb[row * 128 + c4 * 4];
  }
}

static __device__ __forceinline__ float keyval(unsigned long long K) {
  const uint32_t mk = ~(uint32_t)(K >> 32);
  const uint32_t sb = (mk & 0x80000000u) ? (mk & 0x7FFFFFFFu) : ~mk;
  return __uint_as_float(sb);
}

// ---------------- rank40: per-row candidate ranking (flash combine) ----------------
__global__ __launch_bounds__(256) void rank40_kernel(const int* __restrict__ cnt,
    const unsigned long long* __restrict__ candbuf, const float* __restrict__ maxpart,
    const float* __restrict__ expsumpart, float* __restrict__ topv,
    int* __restrict__ topi, int* __restrict__ needflag) {
  __shared__ unsigned long long keys[1280];
  __shared__ int bases[9];
  __shared__ int okflag;
  __shared__ int nab;
  const int r = blockIdx.x, t = threadIdx.x, l = t & 63;
  if (t == 0) {
    int tot = 0, ok = 1;
    for (int c = 0; c < 8; c++) {
      bases[c] = tot;
      const int n = cnt[r * 8 + c];
      if (n > 160) ok = 0;
      tot += (n > 160 ? 160 : n);
    }
    bases[8] = tot;
    okflag = ok ? tot : -1;
    nab = 0;
  }
  __syncthreads();
  const int total = okflag;
  if (total < 0) { if (t == 0) needflag[r] = 1; return; }
  float rm = -3.0e38f;
  float mp[8];
#pragma unroll
  for (int c = 0; c < 8; c++) { mp[c] = maxpart[c * 4096 + r]; rm = fmaxf(rm, mp[c]); }
  float gsum = 0.f;
#pragma unroll
  for (int c = 0; c < 8; c++) gsum += expsumpart[c * 4096 + r] * expf(mp[c] - rm);
#pragma unroll
  for (int c = 0; c < 8; c++) {
    const int b0 = bases[c], n = bases[c + 1] - b0;
    for (int i = t; i < n; i += 256) keys[b0 + i] = candbuf[((size_t)r * 8 + c) * 160 + i];
  }
  __syncthreads();
  const float thr = rm - 2.0f;
  int myab = 0;
  for (int i = t; i < total; i += 256) myab += (keyval(keys[i]) >= thr) ? 1 : 0;
#pragma unroll
  for (int off = 32; off; off >>= 1) myab += __shfl_xor(myab, off);
  if (l == 0) atomicAdd(&nab, myab);
  __syncthreads();
  if (nab < 40) { if (t == 0) needflag[r] = 1; return; }
  if (t == 0) needflag[r] = 0;
  const float rgs = 1.0f / gsum;
  for (int i = t; i < total; i += 256) {
    const unsigned long long K = keys[i];
    int rank = 0;
#pragma unroll 4
    for (int p = 0; p < total; p++) rank += (keys[p] < K) ? 1 : 0;
    if (rank < 40) {
      topi[r * 40 + rank] = (int)(K & 0xFFFFFFFFu);
      topv[r * 40 + rank] = expf(keyval(K) - rm) * rgs;
    }
  }
}

// ---------------- repair: brute-force rows the threshold path missed ----------------
__global__ __launch_bounds__(256) void repair_kernel(const int* __restrict__ needflag,
    const unsigned short* __restrict__ qb, const unsigned short* __restrict__ kT,
    const float* __restrict__ maxpart, const float* __restrict__ expsumpart,
    float* __restrict__ topv, int* __restrict__ topi) {
  const int r = blockIdx.x, t = threadIdx.x, l = t & 63, w = t >> 6;
  if (!needflag[r]) return;
  __shared__ float lg[8192];
  __shared__ float qrow[128];
  __shared__ float sred[4];
  __shared__ int scnt;
  __shared__ unsigned long long keys[2048];
  __shared__ int lc;
  if (t < 128) qrow[t] = bf2f(qb[(size_t)r * 128 + t]);
  __syncthreads();
  for (int j = t; j < 8192; j += 256) {
    float acc = 0.f;
    const unsigned short* kr = kT + (size_t)j * 128;
    for (int k = 0; k < 128; k++) acc += qrow[k] * bf2f(kr[k]);
    lg[j] = acc * RSQ;
  }
  __syncthreads();
  float bm = -3.0e38f;
  for (int j = t; j < 8192; j += 256) bm = fmaxf(bm, lg[j]);
#pragma unroll
  for (int off = 32; off; off >>= 1) bm = fmaxf(bm, __shfl_xor(bm, off));
  if (l == 0) sred[w] = bm;
  __syncthreads();
  bm = fmaxf(fmaxf(sred[0], sred[1]), fmaxf(sred[2], sred[3]));
  float theta = bm;
  for (int trial = 0; trial < 32; trial++) {
    theta = bm - 0.6f * (float)(trial + 1);
    int c = 0;
    for (int j = t; j < 8192; j += 256) c += (lg[j] >= theta) ? 1 : 0;
#pragma unroll
    for (int off = 32; off; off >>= 1) c += __shfl_xor(c, off);
    __syncthreads();
    if (t == 0) scnt = 0;
    __syncthreads();
    if (l == 0) atomicAdd(&scnt, c);
    __syncthreads();
    if (scnt >= 40) break;
  }
  if (t == 0) lc = 0;
  __syncthreads();
  for (int j = t; j < 8192; j += 256) {
    const float v = lg[j];
    if (v >= theta) {
      const int pos = atomicAdd(&lc, 1);
      if (pos < 2048) {
        const uint32_t sb = __float_as_uint(v);
        const uint32_t mk = (sb & 0x80000000u) ? ~sb : (sb | 0x80000000u);
        keys[pos] = ((unsigned long long)(~mk) << 32) | (unsigned)j;
      }
    }
  }
  __syncthreads();
  const int total = min(lc, 2048);
  float rm = -3.0e38f;
  float mp[8];
#pragma unroll
  for (int c = 0; c < 8; c++) { mp[c] = maxpart[c * 4096 + r]; rm = fmaxf(rm, mp[c]); }
  float gsum = 0.f;
#pragma unroll
  for (int c = 0; c < 8; c++) gsum += expsumpart[c * 4096 + r] * expf(mp[c] - rm);
  const float rgs = 1.0f / gsum;
  for (int i = t; i < total; i += 256) {
    const unsigned long long K = keys[i];
    int rank = 0;
    for (int p = 0; p < total; p++) rank += (keys[p] < K) ? 1 : 0;
    if (rank < 40) {
      topi[r * 40 + rank] = (int)(K & 0xFFFFFFFFu);
      topv[r * 40 + rank] = expf(keyval(K) - rm) * rgs;
    }
  }
}

__global__ __launch_bounds__(256) void pvred_kernel(const float* __restrict__ pvpart,
    const float* __restrict__ maxpart, const float* __restrict__ expsumpart,
    float* __restrict__ o2, float* __restrict__ o3) {
  const int idx4 = blockIdx.x * 256 + threadIdx.x;
  const int row = idx4 >> 5;
  float rm = -3.0e38f;
  float mp[8];
#pragma unroll
  for (int c = 0; c < 8; c++) { mp[c] = maxpart[c * 4096 + row]; rm = fmaxf(rm, mp[c]); }
  float gs = 0.f;
#pragma unroll
  for (int c = 0; c < 8; c++) {
    mp[c] = expf(mp[c] - rm);
    gs += expsumpart[c * 4096 + row] * mp[c];
  }
  const float ri = 1.0f / gs;
  float4 s; s.x = s.y = s.z = s.w = 0.f;
#pragma unroll
  for (int ch = 0; ch < 8; ch++) {
    float4 p = *(const float4*)(pvpart + (size_t)ch * 524288 + (size_t)idx4 * 4);
    s.x += p.x * mp[ch]; s.y += p.y * mp[ch]; s.z += p.z * mp[ch]; s.w += p.w * mp[ch];
  }
  s.x *= ri; s.y *= ri; s.z *= ri; s.w *= ri;
  *(float4*)(o2 + (size_t)idx4 * 4) = s;
  *(float4*)(o3 + (size_t)idx4 * 4) = s;
}

__global__ __launch_bounds__(256) void seedscatter_kernel(const int* __restrict__ topi,
    const float* __restrict__ topv, const int* __restrict__ invperm,
    float* __restrict__ out0) {
  const int b = blockIdx.x, t = threadIdx.x;
  int s = 0;
  for (int e = t; e < 640; e += 256) s += topi[b * 640 + e];
#pragma unroll
  for (int off = 32; off; off >>= 1) s += __shfl_xor(s, off);
  __shared__ int sred[4];
  if ((t & 63) == 0) sred[t >> 6] = s;
  __syncthreads();
  const int total = sred[0] + sred[1] + sred[2] + sred[3];
  const float avg = (float)total / 640.0f;
  const int sd = ((int)floorf(avg / 2048.0f)) & 3;
  const int* ip = invperm + sd * 8192;
  for (int e = t; e < 640; e += 256) {
    const int q = e / 40;
    const int i = topi[b * 640 + e];
    const float val = topv[b * 640 + e];
    out0[((size_t)(b * 16 + q)) * 8192 + ip[i]] = val;
  }
}

extern "C" void kernel_launch(void* const* d_in, const int* in_sizes, int n_in,
                              void* d_out, int out_size, void* d_ws, size_t ws_size,
                              hipStream_t stream) {
  const float* x   = (const float*)d_in[0];
  const float* emb = (const float*)d_in[1];
  const float* Wq  = (const float*)d_in[2];
  const float* bq  = (const float*)d_in[3];
  const float* Wv  = (const float*)d_in[4];
  const float* bv  = (const float*)d_in[5];
  const float* bng = (const float*)d_in[6];
  const float* bnb = (const float*)d_in[7];
  const float* lng = (const float*)d_in[8];
  const float* lnb = (const float*)d_in[9];

  float* out0  = (float*)d_out;          // attn_w_flat (sparse)
  float* outq  = out0 + 33554432;        // q
  float* outap = outq + 524288;          // applied
  float* outaf = outap + 524288;         // applied_flat

  float* wsf        = (float*)d_ws;
  float* kbuf       = wsf;                     // 1048576
  float* vbuf       = kbuf + 1048576;          // 1048576
  float* qraw       = vbuf + 1048576;          // 524288
  float* bnpart     = qraw + 524288;           // 8192
  float* bnstat     = bnpart + 8192;           // 256
  float* maxpart    = bnstat + 256;            // 32768 (8x4096)
  float* expsumpart = maxpart + 32768;         // 32768 (8x4096)
  float* pvpart     = expsumpart + 32768;      // 8*524288 = 4194304
  float* topv       = pvpart + 4194304;        // 163840
  int*   topi       = (int*)(topv + 163840);   // 163840
  int*   cnt        = topi + 163840;           // 32768 (4096x8)
  int*   needflag   = cnt + 32768;             // 4096
  int*   invperm    = needflag + 4096;         // 32768
  int*   rankbuf    = invperm + 32768;         // 65536
  unsigned short* qb = (unsigned short*)(rankbuf + 65536);  // 524288 ushort
  unsigned short* kT = qb + 524288;                         // 1048576 ushort
  unsigned short* vT = kT + 1048576;                        // 1048576 ushort
  unsigned long long* candbuf = (unsigned long long*)(vT + 1048576);  // 4096*8*160

  hipMemsetAsync(out0, 0, (size_t)33554432 * 4, stream);
  hipMemsetAsync(cnt, 0, (size_t)36864 * 4, stream);  // cnt + needflag
  rank_kernel<<<dim3(32, 2, 4), 256, 0, stream>>>(rankbuf);
  compose_kernel<<<dim3(32, 4), 256, 0, stream>>>(rankbuf, invperm);
  qraw_kernel<<<dim3(64, 4), 256, 0, stream>>>(x, Wq, bq, qraw);
  bnpart_kernel<<<32, 256, 0, stream>>>(qraw, bnpart);
  bnfin_kernel<<<1, 128, 0, stream>>>(bnpart, bng, bnb, bnstat);
  qnorm_kernel<<<512, 256, 0, stream>>>(qraw, bnstat, outq, qb);
  lnv_kernel<<<512, 256, 0, stream>>>(emb, Wv, bv, lng, lnb, kbuf, vbuf);
  kvtrans_kernel<<<dim3(128, 2), 256, 0, stream>>>(kbuf, vbuf, kT, vT);
  attn_flash<<<dim3(8, 64), 256, 0, stream>>>(qb, kT, vT, pvpart, maxpart,
                                              expsumpart, candbuf, cnt);
  rank40_kernel<<<4096, 256, 0, stream>>>(cnt, candbuf, maxpart, expsumpart,
                                          topv, topi, needflag);
  repair_kernel<<<4096, 256, 0, stream>>>(needflag, qb, kT, maxpart, expsumpart,
                                          topv, topi);
  pvred_kernel<<<512, 256, 0, stream>>>(pvpart, maxpart, expsumpart, outap, outaf);
  seedscatter_kernel<<<256, 256, 0, stream>>>(topi, topv, invperm, out0);
}

// Round 8
// 784.277 us; speedup vs baseline: 2.3118x; 2.3118x over previous
//
#include <hip/hip_runtime.h>
#include <hip/hip_bf16.h>
#include <stdint.h>

// N=8192, C1=512, C2=128, M=4, B=256, TOPK=40, R=B*M*M=4096
#define EPSF 1e-5f
#define RSQ 0.08838834764831845f  // 1/sqrt(128)

typedef __bf16 b16x8 __attribute__((ext_vector_type(8)));
typedef float f32x4 __attribute__((ext_vector_type(4)));
typedef unsigned short u16x8 __attribute__((ext_vector_type(8)));

static __device__ __forceinline__ unsigned short f2bf(float f) {
  __hip_bfloat16 h = __float2bfloat16(f);
  return __builtin_bit_cast(unsigned short, h);
}
static __device__ __forceinline__ float bf2f(unsigned short u) {
  union { unsigned int i; float f; } x; x.i = ((unsigned int)u) << 16; return x.f;
}

// ---------------- RNG (JAX threefry, partitionable) ----------------
__device__ __forceinline__ void threefry2x32(uint32_t k0, uint32_t k1,
                                             uint32_t c0, uint32_t c1,
                                             uint32_t& o0, uint32_t& o1) {
  const uint32_t ks2 = k0 ^ k1 ^ 0x1BD11BDAu;
  uint32_t x0 = c0 + k0, x1 = c1 + k1;
#define TFR(r) { x0 += x1; x1 = (x1 << (r)) | (x1 >> (32 - (r))); x1 ^= x0; }
  TFR(13) TFR(15) TFR(26) TFR(6)
  x0 += k1;  x1 += ks2 + 1u;
  TFR(17) TFR(29) TFR(16) TFR(24)
  x0 += ks2; x1 += k0 + 2u;
  TFR(13) TFR(15) TFR(26) TFR(6)
  x0 += k0;  x1 += k1 + 3u;
  TFR(17) TFR(29) TFR(16) TFR(24)
  x0 += k1;  x1 += ks2 + 4u;
  TFR(13) TFR(15) TFR(26) TFR(6)
  x0 += ks2; x1 += k0 + 5u;
#undef TFR
  o0 = x0; o1 = x1;
}

// rank-based permutation: invperm[s][v] = rank2[rank1[v]]
__global__ __launch_bounds__(256) void rank_kernel(int* __restrict__ rankbuf) {
  __shared__ uint32_t bits[8192];
  const int chunk = blockIdx.x;
  const int round = blockIdx.y;
  const int s     = blockIdx.z;
  const int t = threadIdx.x, l = t & 63, w = t >> 6;
  uint32_t ka, kb;
  {
    uint32_t k1a, k1b;
    threefry2x32(0u, (uint32_t)s, 0u, 0u, k1a, k1b);
    if (round == 0) threefry2x32(0u, (uint32_t)s, 0u, 1u, ka, kb);
    else            threefry2x32(k1a, k1b, 0u, 1u, ka, kb);
  }
  for (int j = t; j < 8192; j += 256) {
    uint32_t t0, t1;
    threefry2x32(ka, kb, 0u, (uint32_t)j, t0, t1);
    bits[j] = t1;
  }
  __syncthreads();
  const int base = chunk * 256 + w * 64;
  const int i = base + l;
  const uint32_t myb = bits[i];
  const uint4* b4 = (const uint4*)bits;
  int rk = 0;
  const int lo = base >> 2;
#pragma unroll 4
  for (int j4 = 0; j4 < lo; j4++) {
    const uint4 b = b4[j4];
    rk += (b.x <= myb) + (b.y <= myb) + (b.z <= myb) + (b.w <= myb);
  }
#pragma unroll
  for (int j4 = lo; j4 < lo + 16; j4++) {
    const uint4 b = b4[j4];
    const int j = j4 * 4;
    rk += (b.x < myb) + ((b.x == myb) && (j     < i));
    rk += (b.y < myb) + ((b.y == myb) && (j + 1 < i));
    rk += (b.z < myb) + ((b.z == myb) && (j + 2 < i));
    rk += (b.w < myb) + ((b.w == myb) && (j + 3 < i));
  }
#pragma unroll 4
  for (int j4 = lo + 16; j4 < 2048; j4++) {
    const uint4 b = b4[j4];
    rk += (b.x < myb) + (b.y < myb) + (b.z < myb) + (b.w < myb);
  }
  rankbuf[(s * 2 + round) * 8192 + i] = rk;
}

__global__ __launch_bounds__(256) void compose_kernel(const int* __restrict__ rankbuf,
                                                      int* __restrict__ invperm) {
  const int s = blockIdx.y;
  const int v = blockIdx.x * 256 + threadIdx.x;
  const int* r1 = rankbuf + s * 16384;
  const int* r2 = r1 + 8192;
  invperm[s * 8192 + v] = r2[r1[v]];
}

// ---------------- q path ----------------
__global__ __launch_bounds__(256) void qraw_kernel(const float* __restrict__ x,
    const float* __restrict__ Wq, const float* __restrict__ bq,
    float* __restrict__ qraw) {
  __shared__ float ea[16][128];
  __shared__ float wq[128][132];
  const int t = threadIdx.x;
  const int g = blockIdx.x;
  const int m2 = blockIdx.y;
  for (int i = t; i < 512; i += 256) {
    float4 xx = *(const float4*)(x + (size_t)g * 2048 + i * 4);
    *(float4*)&ea[i >> 5][(i & 31) * 4] = xx;
  }
  for (int i = t; i < 4096; i += 256) {
    float4 ww = *(const float4*)(Wq + (size_t)m2 * 16384 + i * 4);
    *(float4*)&wq[i >> 5][(i & 31) * 4] = ww;
  }
  __syncthreads();
  const int row = t >> 4, j = t & 15;
  float acc[8] = {0.f,0.f,0.f,0.f,0.f,0.f,0.f,0.f};
  for (int d = 0; d < 128; d++) {
    const float xv = ea[row][d];
#pragma unroll
    for (int cc = 0; cc < 8; cc++) acc[cc] += xv * wq[j + cc * 16][d];
  }
  const int r = (g * 16 + row) * 4 + m2;
#pragma unroll
  for (int cc = 0; cc < 8; cc++) {
    const int c = j + cc * 16;
    qraw[(size_t)r * 128 + c] = acc[cc] + bq[m2 * 128 + c];
  }
}

__global__ __launch_bounds__(256) void bnpart_kernel(const float* __restrict__ qraw,
                                                     float* __restrict__ bnpart) {
  __shared__ float a1[256], a2[256];
  const int t = threadIdx.x, c = t & 127, h = t >> 7;
  float s1 = 0.f, s2 = 0.f;
  for (int i = 0; i < 64; i++) {
    float xv = qraw[(size_t)(blockIdx.x * 128 + h + 2 * i) * 128 + c];
    s1 += xv; s2 += xv * xv;
  }
  a1[t] = s1; a2[t] = s2;
  __syncthreads();
  if (t < 128) {
    bnpart[blockIdx.x * 256 + t]       = a1[t] + a1[t + 128];
    bnpart[blockIdx.x * 256 + 128 + t] = a2[t] + a2[t + 128];
  }
}

__global__ void bnfin_kernel(const float* __restrict__ bnpart,
                             const float* __restrict__ gamma,
                             const float* __restrict__ beta,
                             float* __restrict__ bnstat) {
  const int c = threadIdx.x;
  float s1 = 0.f, s2 = 0.f;
  for (int i = 0; i < 32; i++) { s1 += bnpart[i * 256 + c]; s2 += bnpart[i * 256 + 128 + c]; }
  const float mu  = s1 * (1.0f / 4096.0f);
  const float var = s2 * (1.0f / 4096.0f) - mu * mu;
  const float sc  = rsqrtf(var + EPSF) * gamma[c];
  bnstat[c]       = sc;
  bnstat[128 + c] = beta[c] - mu * sc;
}

__global__ __launch_bounds__(256) void qnorm_kernel(const float* __restrict__ qraw,
    const float* __restrict__ bnstat, float* __restrict__ outq,
    unsigned short* __restrict__ qb) {
  const int idx4 = blockIdx.x * 256 + threadIdx.x;
  float4 xv = *(const float4*)(qraw + (size_t)idx4 * 4);
  const int c0 = (idx4 * 4) & 127;
  float4 sc = *(const float4*)(bnstat + c0);
  float4 sh = *(const float4*)(bnstat + 128 + c0);
  float4 o;
  o.x = xv.x * sc.x + sh.x; o.y = xv.y * sc.y + sh.y;
  o.z = xv.z * sc.z + sh.z; o.w = xv.w * sc.w + sh.w;
  *(float4*)(outq + (size_t)idx4 * 4) = o;
  ushort4 ob;
  ob.x = f2bf(o.x); ob.y = f2bf(o.y); ob.z = f2bf(o.z); ob.w = f2bf(o.w);
  *(ushort4*)(qb + (size_t)idx4 * 4) = ob;
}

// ---------------- LN(emb) -> kbuf, emb@Wv^T+bv -> vbuf ----------------
__global__ __launch_bounds__(256) void lnv_kernel(const float* __restrict__ emb,
    const float* __restrict__ Wv, const float* __restrict__ bv,
    const float* __restrict__ lng, const float* __restrict__ lnb,
    float* __restrict__ kbuf, float* __restrict__ vbuf) {
  __shared__ float ea[16][128];
  __shared__ float wv[128][132];
  const int t = threadIdx.x;
  const int r0 = blockIdx.x * 16;
  for (int i = t; i < 512; i += 256) {
    float4 xx = *(const float4*)(emb + (size_t)r0 * 128 + i * 4);
    *(float4*)&ea[i >> 5][(i & 31) * 4] = xx;
  }
  for (int i = t; i < 4096; i += 256) {
    float4 ww = *(const float4*)(Wv + (size_t)i * 4);
    *(float4*)&wv[i >> 5][(i & 31) * 4] = ww;
  }
  __syncthreads();
  const int row = t >> 4, j = t & 15;
  float s1 = 0.f, s2 = 0.f;
#pragma unroll
  for (int m = 0; m < 8; m++) { float xv = ea[row][j + m * 16]; s1 += xv; s2 += xv * xv; }
#pragma unroll
  for (int off = 8; off; off >>= 1) {
    s1 += __shfl_xor(s1, off, 16);
    s2 += __shfl_xor(s2, off, 16);
  }
  const float mu   = s1 * 0.0078125f;
  const float var  = s2 * 0.0078125f - mu * mu;
  const float rstd = rsqrtf(var + EPSF);
#pragma unroll
  for (int m = 0; m < 8; m++) {
    const int d = j + m * 16;
    kbuf[(size_t)(r0 + row) * 128 + d] = (ea[row][d] - mu) * rstd * lng[d] + lnb[d];
  }
  float acc[8] = {0.f,0.f,0.f,0.f,0.f,0.f,0.f,0.f};
  for (int d = 0; d < 128; d++) {
    const float xv = ea[row][d];
#pragma unroll
    for (int cc = 0; cc < 8; cc++) acc[cc] += xv * wv[j + cc * 16][d];
  }
#pragma unroll
  for (int cc = 0; cc < 8; cc++) {
    const int c = j + cc * 16;
    vbuf[(size_t)(r0 + row) * 128 + c] = acc[cc] + bv[c];
  }
}

// ---------------- bf16 transposes (merged): y=0 -> kT, y=1 -> vT ----------------
__global__ __launch_bounds__(256) void kvtrans_kernel(const float* __restrict__ kbuf,
    const float* __restrict__ vbuf, unsigned short* __restrict__ kT,
    unsigned short* __restrict__ vT) {
  __shared__ __attribute__((aligned(16))) unsigned short sbuf[9216];
  const int b = blockIdx.x, t = threadIdx.x;
  if (blockIdx.y == 0) {
    unsigned short (*s)[136] = (unsigned short (*)[136])sbuf;
    const int k = t >> 1, half = t & 1;
    const float* src = kbuf + (size_t)(k * 64 + (b >> 1)) * 128 + (b & 1) * 64 + half * 32;
#pragma unroll
    for (int i = 0; i < 8; i++) {
      float4 v = *(const float4*)(src + i * 4);
      const int dn = half * 32 + i * 4;
      s[dn + 0][k] = f2bf(v.x); s[dn + 1][k] = f2bf(v.y);
      s[dn + 2][k] = f2bf(v.z); s[dn + 3][k] = f2bf(v.w);
    }
    __syncthreads();
    const int dn = t >> 2, q = t & 3;
    unsigned short* dst = kT + (size_t)(b * 64 + dn) * 128 + q * 32;
#pragma unroll
    for (int j = 0; j < 4; j++)
      *(int4*)(dst + j * 8) = *(const int4*)&s[dn][q * 32 + j * 8];
  } else {
    unsigned short (*s)[72] = (unsigned short (*)[72])sbuf;
    const int i0 = b * 64;
    const int di = t >> 2, q = t & 3;
    const float* src = vbuf + (size_t)(i0 + di) * 128 + q * 32;
#pragma unroll
    for (int i = 0; i < 8; i++) {
      float4 v = *(const float4*)(src + i * 4);
      const int c = q * 32 + i * 4;
      s[c + 0][di] = f2bf(v.x); s[c + 1][di] = f2bf(v.y);
      s[c + 2][di] = f2bf(v.z); s[c + 3][di] = f2bf(v.w);
    }
    __syncthreads();
    const int c = t >> 1, half = t & 1;
    unsigned short* dst = vT + (size_t)c * 8192 + i0 + half * 32;
#pragma unroll
    for (int j = 0; j < 4; j++)
      *(int4*)(dst + j * 8) = *(const int4*)&s[c][half * 32 + j * 8];
  }
}

// ---------------- attn_flash: online-softmax QK^T + PV (no candidates) ----------------
// grid (8, 64), block 256 (4 waves, 2 row x 2 col). Per block: 64 rows x 1024 cols.
// Running max m is SHARED per row across the two wc waves each tile.
__global__ __launch_bounds__(256, 2) void attn_flash(
    const unsigned short* __restrict__ qb, const unsigned short* __restrict__ kT,
    const unsigned short* __restrict__ vT, float* __restrict__ pvpart,
    float* __restrict__ maxpart, float* __restrict__ expsumpart) {
  __shared__ __attribute__((aligned(16))) unsigned short kvt[16384];  // [128][128] 32KB
  __shared__ __attribute__((aligned(16))) unsigned short pt[8192];    // [64][128] 16KB
  __shared__ float mred[64][2], esred[64][2];
  const int t = threadIdx.x, l = t & 63, w = t >> 6;
  const int bx = blockIdx.x;          // k-chunk, 1024 cols
  const int r0g = blockIdx.y * 64;    // global row base
  const int n0 = bx * 1024;
  const int wr = w >> 1, wc = w & 1;
  float m[2][4], es[2][4];
  f32x4 pv[2][4];
#pragma unroll
  for (int i = 0; i < 2; i++)
#pragma unroll
    for (int jj = 0; jj < 4; jj++) { m[i][jj] = -3.0e38f; es[i][jj] = 0.f; }
#pragma unroll
  for (int i = 0; i < 2; i++)
#pragma unroll
    for (int j = 0; j < 4; j++) pv[i][j] = (f32x4){0.f, 0.f, 0.f, 0.f};

  for (int ct = 0; ct < 8; ct++) {
    __syncthreads();
#pragma unroll
    for (int it = 0; it < 8; it++) {
      const int c = it * 256 + t;
      const int row = c >> 4, ch = c & 15, chs = ch ^ (row & 7);
      const unsigned short* g = kT + (size_t)(n0 + ct * 128 + row) * 128 + chs * 8;
      __builtin_amdgcn_global_load_lds((const __attribute__((address_space(1))) void*)g,
          (__attribute__((address_space(3))) void*)(kvt + (size_t)(it * 256 + w * 64) * 8), 16, 0, 0);
    }
    __syncthreads();
    f32x4 sacc[2][4];
#pragma unroll
    for (int i = 0; i < 2; i++)
#pragma unroll
      for (int j = 0; j < 4; j++) sacc[i][j] = (f32x4){0.f, 0.f, 0.f, 0.f};
#pragma unroll
    for (int ks = 0; ks < 4; ks++) {
      b16x8 a0 = __builtin_bit_cast(b16x8,
          *(const u16x8*)(qb + (size_t)(r0g + wr * 32 + (l & 15)) * 128 + ks * 32 + (l >> 4) * 8));
      b16x8 a1 = __builtin_bit_cast(b16x8,
          *(const u16x8*)(qb + (size_t)(r0g + wr * 32 + 16 + (l & 15)) * 128 + ks * 32 + (l >> 4) * 8));
#pragma unroll
      for (int j = 0; j < 4; j++) {
        const int cl = wc * 64 + j * 16 + (l & 15);
        const int ch = (ks * 4 + (l >> 4)) ^ (cl & 7);
        b16x8 bf = __builtin_bit_cast(b16x8, *(const u16x8*)&kvt[cl * 128 + ch * 8]);
        sacc[0][j] = __builtin_amdgcn_mfma_f32_16x16x32_bf16(a0, bf, sacc[0][j], 0, 0, 0);
        sacc[1][j] = __builtin_amdgcn_mfma_f32_16x16x32_bf16(a1, bf, sacc[1][j], 0, 0, 0);
      }
    }
    // per-row tile max, shared across wc halves
    float tmv[2][4];
#pragma unroll
    for (int i = 0; i < 2; i++)
#pragma unroll
      for (int jj = 0; jj < 4; jj++) {
        float tm = fmaxf(fmaxf(sacc[i][0][jj], sacc[i][1][jj]),
                         fmaxf(sacc[i][2][jj], sacc[i][3][jj])) * RSQ;
#pragma unroll
        for (int off = 8; off; off >>= 1) tm = fmaxf(tm, __shfl_xor(tm, off));
        tmv[i][jj] = tm;
        if ((l & 15) == 0) mred[wr * 32 + i * 16 + (l >> 4) * 4 + jj][wc] = tm;
      }
    __syncthreads();
#pragma unroll
    for (int i = 0; i < 2; i++) {
#pragma unroll
      for (int jj = 0; jj < 4; jj++) {
        const int prow = wr * 32 + i * 16 + (l >> 4) * 4 + jj;
        const float other = mred[prow][wc ^ 1];
        const float nm = fmaxf(m[i][jj], fmaxf(tmv[i][jj], other));
        const float f = expf(m[i][jj] - nm);
        es[i][jj] *= f;
#pragma unroll
        for (int j = 0; j < 4; j++) pv[i][j][jj] *= f;
#pragma unroll
        for (int j = 0; j < 4; j++) {
          const float logit = sacc[i][j][jj] * RSQ;
          const float p = expf(logit - nm);
          es[i][jj] += p;
          const int colb = wc * 64 + j * 16 + (l & 15);
          const int physc = (((colb >> 3) ^ (prow & 7)) << 3) | (colb & 7);
          pt[prow * 128 + physc] = f2bf(p);
        }
        m[i][jj] = nm;
      }
    }
    __syncthreads();
#pragma unroll
    for (int it = 0; it < 8; it++) {
      const int c = it * 256 + t;
      const int row = c >> 4, ch = c & 15, chs = ch ^ (row & 7);
      const unsigned short* g = vT + (size_t)row * 8192 + n0 + ct * 128 + chs * 8;
      __builtin_amdgcn_global_load_lds((const __attribute__((address_space(1))) void*)g,
          (__attribute__((address_space(3))) void*)(kvt + (size_t)(it * 256 + w * 64) * 8), 16, 0, 0);
    }
    __syncthreads();
#pragma unroll
    for (int ks = 0; ks < 4; ks++) {
      b16x8 paf[2];
#pragma unroll
      for (int i = 0; i < 2; i++) {
        const int rl = wr * 32 + i * 16 + (l & 15);
        const int ch = (ks * 4 + (l >> 4)) ^ (rl & 7);
        paf[i] = __builtin_bit_cast(b16x8, *(const u16x8*)&pt[rl * 128 + ch * 8]);
      }
#pragma unroll
      for (int j = 0; j < 4; j++) {
        const int cl = wc * 64 + j * 16 + (l & 15);
        const int ch = (ks * 4 + (l >> 4)) ^ (cl & 7);
        b16x8 vbf = __builtin_bit_cast(b16x8, *(const u16x8*)&kvt[cl * 128 + ch * 8]);
        pv[0][j] = __builtin_amdgcn_mfma_f32_16x16x32_bf16(paf[0], vbf, pv[0][j], 0, 0, 0);
        pv[1][j] = __builtin_amdgcn_mfma_f32_16x16x32_bf16(paf[1], vbf, pv[1][j], 0, 0, 0);
      }
    }
  }
  __syncthreads();
#pragma unroll
  for (int i = 0; i < 2; i++)
#pragma unroll
    for (int jj = 0; jj < 4; jj++) {
      float e = es[i][jj];
#pragma unroll
      for (int off = 8; off; off >>= 1) e += __shfl_xor(e, off);
      if ((l & 15) == 0) {
        const int row = wr * 32 + i * 16 + (l >> 4) * 4 + jj;
        mred[row][wc] = m[i][jj];
        esred[row][wc] = e;
      }
    }
  __syncthreads();
  if (t < 64) {
    const float m0 = mred[t][0], m1 = mred[t][1];
    const float M = fmaxf(m0, m1);
    const float E = esred[t][0] * expf(m0 - M) + esred[t][1] * expf(m1 - M);
    maxpart[bx * 4096 + r0g + t] = M;
    expsumpart[bx * 4096 + r0g + t] = E;
    mred[t][0] = M;
  }
  __syncthreads();
  float* fb = (float*)kvt;
#pragma unroll
  for (int i = 0; i < 2; i++)
#pragma unroll
    for (int jj = 0; jj < 4; jj++) {
      const int row = wr * 32 + i * 16 + (l >> 4) * 4 + jj;
      const float sc = expf(m[i][jj] - mred[row][0]);
#pragma unroll
      for (int j = 0; j < 4; j++)
        fb[row * 128 + wc * 64 + j * 16 + (l & 15)] = pv[i][j][jj] * sc;
    }
  __syncthreads();
#pragma unroll
  for (int kk = 0; kk < 8; kk++) {
    const int idx4 = kk * 256 + t;
    const int row = idx4 >> 5, c4 = idx4 & 31;
    *(float4*)(pvpart + ((size_t)bx * 4096 + r0g + row) * 128 + c4 * 4) = *(const float4*)&fb[row * 128 + c4 * 4];
  }
}

__global__ __launch_bounds__(256) void rowmax_fin_kernel(const float* __restrict__ maxpart,
                                                         float* __restrict__ rowmax) {
  const int idx = blockIdx.x * 256 + threadIdx.x;
  float m = -3.0e38f;
#pragma unroll
  for (int c = 0; c < 8; c++) m = fmaxf(m, maxpart[c * 4096 + idx]);
  rowmax[idx] = m;  // maxpart already logit-scale
}

// ---------------- collect: QK^T (MFMA) + exact-threshold candidate append ----------------
// grid (8, 64), block 256. Same tiling as attn_flash's QK^T phase; register-light.
__global__ __launch_bounds__(256, 2) void collect_kernel(
    const unsigned short* __restrict__ qb, const unsigned short* __restrict__ kT,
    const float* __restrict__ rowmax, unsigned long long* __restrict__ candbuf,
    int* __restrict__ cnt) {
  __shared__ __attribute__((aligned(16))) unsigned short kvt[16384];
  __shared__ float thr[64];
  const int t = threadIdx.x, l = t & 63, w = t >> 6;
  const int bx = blockIdx.x;
  const int r0g = blockIdx.y * 64;
  const int n0 = bx * 1024;
  const int wr = w >> 1, wc = w & 1;
  if (t < 64) thr[t] = rowmax[r0g + t] - 2.0f;

  for (int ct = 0; ct < 8; ct++) {
    __syncthreads();
#pragma unroll
    for (int it = 0; it < 8; it++) {
      const int c = it * 256 + t;
      const int row = c >> 4, ch = c & 15, chs = ch ^ (row & 7);
      const unsigned short* g = kT + (size_t)(n0 + ct * 128 + row) * 128 + chs * 8;
      __builtin_amdgcn_global_load_lds((const __attribute__((address_space(1))) void*)g,
          (__attribute__((address_space(3))) void*)(kvt + (size_t)(it * 256 + w * 64) * 8), 16, 0, 0);
    }
    __syncthreads();
    f32x4 sacc[2][4];
#pragma unroll
    for (int i = 0; i < 2; i++)
#pragma unroll
      for (int j = 0; j < 4; j++) sacc[i][j] = (f32x4){0.f, 0.f, 0.f, 0.f};
#pragma unroll
    for (int ks = 0; ks < 4; ks++) {
      b16x8 a0 = __builtin_bit_cast(b16x8,
          *(const u16x8*)(qb + (size_t)(r0g + wr * 32 + (l & 15)) * 128 + ks * 32 + (l >> 4) * 8));
      b16x8 a1 = __builtin_bit_cast(b16x8,
          *(const u16x8*)(qb + (size_t)(r0g + wr * 32 + 16 + (l & 15)) * 128 + ks * 32 + (l >> 4) * 8));
#pragma unroll
      for (int j = 0; j < 4; j++) {
        const int cl = wc * 64 + j * 16 + (l & 15);
        const int ch = (ks * 4 + (l >> 4)) ^ (cl & 7);
        b16x8 bf = __builtin_bit_cast(b16x8, *(const u16x8*)&kvt[cl * 128 + ch * 8]);
        sacc[0][j] = __builtin_amdgcn_mfma_f32_16x16x32_bf16(a0, bf, sacc[0][j], 0, 0, 0);
        sacc[1][j] = __builtin_amdgcn_mfma_f32_16x16x32_bf16(a1, bf, sacc[1][j], 0, 0, 0);
      }
    }
#pragma unroll
    for (int i = 0; i < 2; i++)
#pragma unroll
      for (int jj = 0; jj < 4; jj++) {
        const int prow = wr * 32 + i * 16 + (l >> 4) * 4 + jj;
        const float th = thr[prow];
#pragma unroll
        for (int j = 0; j < 4; j++) {
          const float logit = sacc[i][j][jj] * RSQ;
          if (logit >= th) {
            const int rg = r0g + prow;
            const int pos = atomicAdd(&cnt[rg * 8 + bx], 1);
            if (pos < 160) {
              const uint32_t sb = __float_as_uint(logit);
              const uint32_t mk = (sb & 0x80000000u) ? ~sb : (sb | 0x80000000u);
              candbuf[((size_t)rg * 8 + bx) * 160 + pos] =
                  ((unsigned long long)(~mk) << 32) |
                  (unsigned)(n0 + ct * 128 + wc * 64 + j * 16 + (l & 15));
            }
          }
        }
      }
  }
}

static __device__ __forceinline__ float keyval(unsigned long long K) {
  const uint32_t mk = ~(uint32_t)(K >> 32);
  const uint32_t sb = (mk & 0x80000000u) ? (mk & 0x7FFFFFFFu) : ~mk;
  return __uint_as_float(sb);
}

// ---------------- rank40: per-row candidate ranking (flash combine) ----------------
__global__ __launch_bounds__(256) void rank40_kernel(const int* __restrict__ cnt,
    const unsigned long long* __restrict__ candbuf, const float* __restrict__ maxpart,
    const float* __restrict__ expsumpart, float* __restrict__ topv,
    int* __restrict__ topi, int* __restrict__ needflag) {
  __shared__ unsigned long long keys[1280];
  __shared__ int bases[9];
  __shared__ int okflag;
  const int r = blockIdx.x, t = threadIdx.x;
  if (t == 0) {
    int tot = 0, ok = 1;
    for (int c = 0; c < 8; c++) {
      bases[c] = tot;
      const int n = cnt[r * 8 + c];
      if (n > 160) ok = 0;
      tot += (n > 160 ? 160 : n);
    }
    bases[8] = tot;
    okflag = (ok && tot >= 40) ? tot : -1;
    needflag[r] = (okflag < 0) ? 1 : 0;
  }
  __syncthreads();
  const int total = okflag;
  if (total < 0) return;
  float rm = -3.0e38f;
  float mp[8];
#pragma unroll
  for (int c = 0; c < 8; c++) { mp[c] = maxpart[c * 4096 + r]; rm = fmaxf(rm, mp[c]); }
  float gsum = 0.f;
#pragma unroll
  for (int c = 0; c < 8; c++) gsum += expsumpart[c * 4096 + r] * expf(mp[c] - rm);
#pragma unroll
  for (int c = 0; c < 8; c++) {
    const int b0 = bases[c], n = bases[c + 1] - b0;
    for (int i = t; i < n; i += 256) keys[b0 + i] = candbuf[((size_t)r * 8 + c) * 160 + i];
  }
  __syncthreads();
  const float rgs = 1.0f / gsum;
  for (int i = t; i < total; i += 256) {
    const unsigned long long K = keys[i];
    int rank = 0;
#pragma unroll 4
    for (int p = 0; p < total; p++) rank += (keys[p] < K) ? 1 : 0;
    if (rank < 40) {
      topi[r * 40 + rank] = (int)(K & 0xFFFFFFFFu);
      topv[r * 40 + rank] = expf(keyval(K) - rm) * rgs;
    }
  }
}

// ---------------- repair: brute-force fallback (normally inactive) ----------------
__global__ __launch_bounds__(256) void repair_kernel(const int* __restrict__ needflag,
    const unsigned short* __restrict__ qb, const unsigned short* __restrict__ kT,
    const float* __restrict__ maxpart, const float* __restrict__ expsumpart,
    float* __restrict__ topv, int* __restrict__ topi) {
  const int r = blockIdx.x, t = threadIdx.x, l = t & 63, w = t >> 6;
  if (!needflag[r]) return;
  __shared__ float lg[8192];
  __shared__ float qrow[128];
  __shared__ float sred[4];
  __shared__ int scnt;
  __shared__ unsigned long long keys[2048];
  __shared__ int lc;
  if (t < 128) qrow[t] = bf2f(qb[(size_t)r * 128 + t]);
  __syncthreads();
  for (int j = t; j < 8192; j += 256) {
    float acc = 0.f;
    const unsigned short* kr = kT + (size_t)j * 128;
    for (int k = 0; k < 128; k++) acc += qrow[k] * bf2f(kr[k]);
    lg[j] = acc * RSQ;
  }
  __syncthreads();
  float bm = -3.0e38f;
  for (int j = t; j < 8192; j += 256) bm = fmaxf(bm, lg[j]);
#pragma unroll
  for (int off = 32; off; off >>= 1) bm = fmaxf(bm, __shfl_xor(bm, off));
  if (l == 0) sred[w] = bm;
  __syncthreads();
  bm = fmaxf(fmaxf(sred[0], sred[1]), fmaxf(sred[2], sred[3]));
  float theta = bm;
  for (int trial = 0; trial < 32; trial++) {
    theta = bm - 0.6f * (float)(trial + 1);
    int c = 0;
    for (int j = t; j < 8192; j += 256) c += (lg[j] >= theta) ? 1 : 0;
#pragma unroll
    for (int off = 32; off; off >>= 1) c += __shfl_xor(c, off);
    __syncthreads();
    if (t == 0) scnt = 0;
    __syncthreads();
    if (l == 0) atomicAdd(&scnt, c);
    __syncthreads();
    if (scnt >= 40) break;
  }
  if (t == 0) lc = 0;
  __syncthreads();
  for (int j = t; j < 8192; j += 256) {
    const float v = lg[j];
    if (v >= theta) {
      const int pos = atomicAdd(&lc, 1);
      if (pos < 2048) {
        const uint32_t sb = __float_as_uint(v);
        const uint32_t mk = (sb & 0x80000000u) ? ~sb : (sb | 0x80000000u);
        keys[pos] = ((unsigned long long)(~mk) << 32) | (unsigned)j;
      }
    }
  }
  __syncthreads();
  const int total = min(lc, 2048);
  float rm = -3.0e38f;
  float mp[8];
#pragma unroll
  for (int c = 0; c < 8; c++) { mp[c] = maxpart[c * 4096 + r]; rm = fmaxf(rm, mp[c]); }
  float gsum = 0.f;
#pragma unroll
  for (int c = 0; c < 8; c++) gsum += expsumpart[c * 4096 + r] * expf(mp[c] - rm);
  const float rgs = 1.0f / gsum;
  for (int i = t; i < total; i += 256) {
    const unsigned long long K = keys[i];
    int rank = 0;
    for (int p = 0; p < total; p++) rank += (keys[p] < K) ? 1 : 0;
    if (rank < 40) {
      topi[r * 40 + rank] = (int)(K & 0xFFFFFFFFu);
      topv[r * 40 + rank] = expf(keyval(K) - rm) * rgs;
    }
  }
}

__global__ __launch_bounds__(256) void pvred_kernel(const float* __restrict__ pvpart,
    const float* __restrict__ maxpart, const float* __restrict__ expsumpart,
    float* __restrict__ o2, float* __restrict__ o3) {
  const int idx4 = blockIdx.x * 256 + threadIdx.x;
  const int row = idx4 >> 5;
  float rm = -3.0e38f;
  float mp[8];
#pragma unroll
  for (int c = 0; c < 8; c++) { mp[c] = maxpart[c * 4096 + row]; rm = fmaxf(rm, mp[c]); }
  float gs = 0.f;
#pragma unroll
  for (int c = 0; c < 8; c++) {
    mp[c] = expf(mp[c] - rm);
    gs += expsumpart[c * 4096 + row] * mp[c];
  }
  const float ri = 1.0f / gs;
  float4 s; s.x = s.y = s.z = s.w = 0.f;
#pragma unroll
  for (int ch = 0; ch < 8; ch++) {
    float4 p = *(const float4*)(pvpart + (size_t)ch * 524288 + (size_t)idx4 * 4);
    s.x += p.x * mp[ch]; s.y += p.y * mp[ch]; s.z += p.z * mp[ch]; s.w += p.w * mp[ch];
  }
  s.x *= ri; s.y *= ri; s.z *= ri; s.w *= ri;
  *(float4*)(o2 + (size_t)idx4 * 4) = s;
  *(float4*)(o3 + (size_t)idx4 * 4) = s;
}

__global__ __launch_bounds__(256) void seedscatter_kernel(const int* __restrict__ topi,
    const float* __restrict__ topv, const int* __restrict__ invperm,
    float* __restrict__ out0) {
  const int b = blockIdx.x, t = threadIdx.x;
  int s = 0;
  for (int e = t; e < 640; e += 256) s += topi[b * 640 + e];
#pragma unroll
  for (int off = 32; off; off >>= 1) s += __shfl_xor(s, off);
  __shared__ int sred[4];
  if ((t & 63) == 0) sred[t >> 6] = s;
  __syncthreads();
  const int total = sred[0] + sred[1] + sred[2] + sred[3];
  const float avg = (float)total / 640.0f;
  const int sd = ((int)floorf(avg / 2048.0f)) & 3;
  const int* ip = invperm + sd * 8192;
  for (int e = t; e < 640; e += 256) {
    const int q = e / 40;
    const int i = topi[b * 640 + e];
    const float val = topv[b * 640 + e];
    out0[((size_t)(b * 16 + q)) * 8192 + ip[i]] = val;
  }
}

extern "C" void kernel_launch(void* const* d_in, const int* in_sizes, int n_in,
                              void* d_out, int out_size, void* d_ws, size_t ws_size,
                              hipStream_t stream) {
  const float* x   = (const float*)d_in[0];
  const float* emb = (const float*)d_in[1];
  const float* Wq  = (const float*)d_in[2];
  const float* bq  = (const float*)d_in[3];
  const float* Wv  = (const float*)d_in[4];
  const float* bv  = (const float*)d_in[5];
  const float* bng = (const float*)d_in[6];
  const float* bnb = (const float*)d_in[7];
  const float* lng = (const float*)d_in[8];
  const float* lnb = (const float*)d_in[9];

  float* out0  = (float*)d_out;          // attn_w_flat (sparse)
  float* outq  = out0 + 33554432;        // q
  float* outap = outq + 524288;          // applied
  float* outaf = outap + 524288;         // applied_flat

  float* wsf        = (float*)d_ws;
  float* kbuf       = wsf;                     // 1048576
  float* vbuf       = kbuf + 1048576;          // 1048576
  float* qraw       = vbuf + 1048576;          // 524288
  float* bnpart     = qraw + 524288;           // 8192
  float* bnstat     = bnpart + 8192;           // 256
  float* rowmax     = bnstat + 256;            // 4096
  float* maxpart    = rowmax + 4096;           // 32768 (8x4096)
  float* expsumpart = maxpart + 32768;         // 32768 (8x4096)
  float* pvpart     = expsumpart + 32768;      // 8*524288 = 4194304
  float* topv       = pvpart + 4194304;        // 163840
  int*   topi       = (int*)(topv + 163840);   // 163840
  int*   cnt        = topi + 163840;           // 32768 (4096x8)
  int*   needflag   = cnt + 32768;             // 4096
  int*   invperm    = needflag + 4096;         // 32768
  int*   rankbuf    = invperm + 32768;         // 65536
  unsigned short* qb = (unsigned short*)(rankbuf + 65536);  // 524288 ushort
  unsigned short* kT = qb + 524288;                         // 1048576 ushort
  unsigned short* vT = kT + 1048576;                        // 1048576 ushort
  unsigned long long* candbuf = (unsigned long long*)(vT + 1048576);  // 4096*8*160

  hipMemsetAsync(out0, 0, (size_t)33554432 * 4, stream);
  hipMemsetAsync(cnt, 0, (size_t)36864 * 4, stream);  // cnt + needflag
  rank_kernel<<<dim3(32, 2, 4), 256, 0, stream>>>(rankbuf);
  compose_kernel<<<dim3(32, 4), 256, 0, stream>>>(rankbuf, invperm);
  qraw_kernel<<<dim3(64, 4), 256, 0, stream>>>(x, Wq, bq, qraw);
  bnpart_kernel<<<32, 256, 0, stream>>>(qraw, bnpart);
  bnfin_kernel<<<1, 128, 0, stream>>>(bnpart, bng, bnb, bnstat);
  qnorm_kernel<<<512, 256, 0, stream>>>(qraw, bnstat, outq, qb);
  lnv_kernel<<<512, 256, 0, stream>>>(emb, Wv, bv, lng, lnb, kbuf, vbuf);
  kvtrans_kernel<<<dim3(128, 2), 256, 0, stream>>>(kbuf, vbuf, kT, vT);
  attn_flash<<<dim3(8, 64), 256, 0, stream>>>(qb, kT, vT, pvpart, maxpart, expsumpart);
  rowmax_fin_kernel<<<16, 256, 0, stream>>>(maxpart, rowmax);
  collect_kernel<<<dim3(8, 64), 256, 0, stream>>>(qb, kT, rowmax, candbuf, cnt);
  rank40_kernel<<<4096, 256, 0, stream>>>(cnt, candbuf, maxpart, expsumpart,
                                          topv, topi, needflag);
  repair_kernel<<<4096, 256, 0, stream>>>(needflag, qb, kT, maxpart, expsumpart,
                                          topv, topi);
  pvred_kernel<<<512, 256, 0, stream>>>(pvpart, maxpart, expsumpart, outap, outaf);
  seedscatter_kernel<<<256, 256, 0, stream>>>(topi, topv, invperm, out0);
}